// Round 2
// baseline (231.382 us; speedup 1.0000x reference)
//
#include <hip/hip_runtime.h>

// DfOp: 5-tap complex FIR along time over first 96 of 481 freq bins, rest copied.
// B=8,T=3000,F=481. Memory-bound: ~278 MB compulsory traffic, ~92 MFLOP.
//
// Layout notes:
//  - row = (b,t) slice, 962 floats. 962 % 4 == 2, so row base alignment mod 16 B
//    alternates by row parity -> float4 needs per-parity offset handling.
//  - coef record = 10 floats per (b,t,f): [cr0..4, ci0..4]. 40 B lane stride is
//    uncoalesced -> stage per-block slice (2560 floats) into LDS with float4.

#define BN   8
#define TN   3000
#define FN   481
#define NDF  96
#define NORD 5
#define ROWF (FN * 2)            // 962 floats per row
#define NROWS (BN * TN)          // 24000
#define NFILT (NROWS * NDF)      // 2,304,000 filtered bins
#define FILT_BLOCKS (NFILT / 256)        // 9000 (exact)
#define COPYU 193                 // per row: 192 float4 + 1 float2
#define NCOPY (NROWS * COPYU)    // 4,632,000 copy units
#define COPY_BLOCKS ((NCOPY + 255) / 256) // 18094

__global__ __launch_bounds__(256) void df_fused(const float* __restrict__ spec,
                                                const float* __restrict__ coef,
                                                float* __restrict__ out) {
    const int blk = blockIdx.x;
    const int tid = threadIdx.x;

    if (blk < FILT_BLOCKS) {
        // ---- filtered band: one thread per (b,t,f) bin ----
        __shared__ __align__(16) float cbuf[256 * 10];   // 10.24 KB
        {
            // cooperative coalesced stage of this block's coef slice (640 float4)
            const float4* src = (const float4*)(coef + (size_t)blk * 2560);
            float4* dst = (float4*)cbuf;
            dst[tid]       = src[tid];
            dst[tid + 256] = src[tid + 256];
            if (tid < 128) dst[tid + 512] = src[tid + 512];
        }
        __syncthreads();

        const int i  = blk * 256 + tid;
        const int f  = i % NDF;
        const int bt = i / NDF;
        const int t  = bt % TN;
        const float* my = cbuf + tid * 10;   // cr[0..4] = my[0..4], ci[k] = my[5+k]
        const int base0 = bt * ROWF + f * 2;

        float fr = 0.f, fi = 0.f;
        if (t >= NORD - 1) {
            #pragma unroll
            for (int k = 0; k < NORD; ++k) {
                const float2 x = *(const float2*)(spec + base0 + (k - 4) * ROWF);
                fr += x.x * my[k]     - x.y * my[5 + k];
                fi += x.x * my[5 + k] + x.y * my[k];
            }
        } else {
            #pragma unroll
            for (int k = 0; k < NORD; ++k) {
                const int tt = t - 4 + k;
                if (tt >= 0) {
                    const float2 x = *(const float2*)(spec + base0 + (k - 4) * ROWF);
                    fr += x.x * my[k]     - x.y * my[5 + k];
                    fi += x.x * my[5 + k] + x.y * my[k];
                }
            }
        }
        *(float2*)(out + base0) = make_float2(fr, fi);
    } else {
        // ---- passthrough copy: f in [96,481), float4-vectorized ----
        const int j = (blk - FILT_BLOCKS) * 256 + tid;
        if (j >= NCOPY) return;
        const int r = j / COPYU;          // row index (b*T+t)
        const int u = j - r * COPYU;      // unit within row
        const int rb = r * ROWF;
        const bool evenRow = (r & 1) == 0;  // row base 16B-aligned iff r even
        if (u < 192) {
            // even row: float4 at [192..960); odd row: float4 at [194..962)
            const int off = rb + (evenRow ? 192 : 194) + 4 * u;
            *(float4*)(out + off) = *(const float4*)(spec + off);
        } else {
            // remaining float2: even row tail at 960, odd row head at 192
            const int off = rb + (evenRow ? 960 : 192);
            *(float2*)(out + off) = *(const float2*)(spec + off);
        }
    }
}

extern "C" void kernel_launch(void* const* d_in, const int* in_sizes, int n_in,
                              void* d_out, int out_size, void* d_ws, size_t ws_size,
                              hipStream_t stream) {
    const float* spec = (const float*)d_in[0];
    const float* coef = (const float*)d_in[1];
    float* out = (float*)d_out;

    const int grid = FILT_BLOCKS + COPY_BLOCKS;
    df_fused<<<grid, 256, 0, stream>>>(spec, coef, out);
}

// Round 3
// 226.998 us; speedup vs baseline: 1.0193x; 1.0193x over previous
//
#include <hip/hip_runtime.h>

// DfOp: 5-tap complex FIR along time over first 96 of 481 freq bins, rest copied.
// B=8,T=3000,F=481. Memory-bound (~278 MB compulsory, ~92 MFLOP).
//
// R3 structure: (1) flat full-tensor float4 copy out=spec (max-BW stream,
// 8 batched loads/thread), then (2) filter kernel overwrites the 96-bin band,
// 2 outputs per thread along t (shared taps, 16 independent loads in flight).
// Stream order guarantees copy-then-overwrite.

#define BN   8
#define TN   3000
#define FN   481
#define NDF  96
#define ROWF (FN * 2)                 // 962 floats per (b,t) row
#define NROWS (BN * TN)               // 24000
#define NT4  ((NROWS * ROWF) / 4)     // 5,772,000 float4 (exact)
#define CPB  2048                     // float4 per copy block (8 per thread)
#define COPY_GRID ((NT4 + CPB - 1) / CPB)   // 2819
#define TPAIRS (TN / 2)               // 1500
#define NFILT_T (BN * TPAIRS * NDF)   // 1,152,000 threads
#define FILT_GRID (NFILT_T / 256)     // 4500 (exact)

__global__ __launch_bounds__(256) void copy_all(const float4* __restrict__ src,
                                                float4* __restrict__ dst) {
    const int base = blockIdx.x * CPB + threadIdx.x;
    if (blockIdx.x < COPY_GRID - 1) {
        float4 v[8];
        #pragma unroll
        for (int k = 0; k < 8; ++k) v[k] = src[base + k * 256];
        #pragma unroll
        for (int k = 0; k < 8; ++k) dst[base + k * 256] = v[k];
    } else {
        float4 v[8];
        #pragma unroll
        for (int k = 0; k < 8; ++k) {
            const int idx = base + k * 256;
            if (idx < NT4) v[k] = src[idx];
        }
        #pragma unroll
        for (int k = 0; k < 8; ++k) {
            const int idx = base + k * 256;
            if (idx < NT4) dst[idx] = v[k];
        }
    }
}

__global__ __launch_bounds__(256) void df_filter(const float* __restrict__ spec,
                                                 const float* __restrict__ coef,
                                                 float* __restrict__ out) {
    const int i  = blockIdx.x * 256 + threadIdx.x;   // < 1,152,000
    const int f  = i % NDF;
    const int r  = i / NDF;
    const int tp = r % TPAIRS;
    const int b  = r / TPAIRS;
    const int t0 = tp * 2;                            // outputs t0, t0+1

    const int row0 = (b * TN + t0) * ROWF + f * 2;    // (b,t0,f,0) flat idx
    const float* sp = spec + row0;

    // 6 shared taps: xs[j] = spec[b, t0-4+j, f] (complex)
    float2 xs[6];
    if (t0 >= 4) {
        #pragma unroll
        for (int j = 0; j < 6; ++j)
            xs[j] = *(const float2*)(sp + (j - 4) * ROWF);
    } else {
        #pragma unroll
        for (int j = 0; j < 6; ++j) {
            const int tt = t0 - 4 + j;
            xs[j] = (tt >= 0) ? *(const float2*)(sp + (j - 4) * ROWF)
                              : make_float2(0.f, 0.f);
        }
    }

    // coef records: 10 floats [cr0..4, ci0..4]
    const float2* c0 = (const float2*)(coef + (size_t)((b * TN + t0) * NDF + f) * 10);
    const float2* c1 = c0 + NDF * 5;                  // next t row
    const float2 a0 = c0[0], a1 = c0[1], a2 = c0[2], a3 = c0[3], a4 = c0[4];
    const float2 b0 = c1[0], b1 = c1[1], b2 = c1[2], b3 = c1[3], b4 = c1[4];
    const float cr0[5] = {a0.x, a0.y, a1.x, a1.y, a2.x};
    const float ci0[5] = {a2.y, a3.x, a3.y, a4.x, a4.y};
    const float cr1[5] = {b0.x, b0.y, b1.x, b1.y, b2.x};
    const float ci1[5] = {b2.y, b3.x, b3.y, b4.x, b4.y};

    float fr0 = 0.f, fi0 = 0.f, fr1 = 0.f, fi1 = 0.f;
    #pragma unroll
    for (int k = 0; k < 5; ++k) {
        const float2 x0 = xs[k];
        fr0 += x0.x * cr0[k] - x0.y * ci0[k];
        fi0 += x0.x * ci0[k] + x0.y * cr0[k];
        const float2 x1 = xs[k + 1];
        fr1 += x1.x * cr1[k] - x1.y * ci1[k];
        fi1 += x1.x * ci1[k] + x1.y * cr1[k];
    }

    *(float2*)(out + row0)        = make_float2(fr0, fi0);
    *(float2*)(out + row0 + ROWF) = make_float2(fr1, fi1);
}

extern "C" void kernel_launch(void* const* d_in, const int* in_sizes, int n_in,
                              void* d_out, int out_size, void* d_ws, size_t ws_size,
                              hipStream_t stream) {
    const float* spec = (const float*)d_in[0];
    const float* coef = (const float*)d_in[1];
    float* out = (float*)d_out;

    copy_all<<<COPY_GRID, 256, 0, stream>>>((const float4*)spec, (float4*)out);
    df_filter<<<FILT_GRID, 256, 0, stream>>>(spec, coef, out);
}